// Round 4
// baseline (56.457 us; speedup 1.0000x reference)
//
#include <hip/hip_runtime.h>
#include <math.h>

#define BB 16384
#define KK_N 32
#define DD 64
#define N_ENT 100000
#define N_REL 32

// ws (floats): [0, N_ENT) ent_scale ; [N_ENT, N_ENT + N_REL*DD) rel table, renormed + swizzled

#define T_ENT  N_ENT
#define T_USER (N_ENT + BB)
#define T_ALL  (N_ENT + BB + N_REL)

__device__ __forceinline__ float dot4(float4 a, float4 b) {
    return a.x * b.x + a.y * b.y + a.z * b.z + a.w * b.w;
}

__device__ __forceinline__ float red16(float ss) {
    ss += __shfl_xor(ss, 1, 64);
    ss += __shfl_xor(ss, 2, 64);
    ss += __shfl_xor(ss, 4, 64);
    ss += __shfl_xor(ss, 8, 64);
    return ss;
}

// one 16-lane group per task
__global__ __launch_bounds__(256) void precompute(
    const float* __restrict__ user_table,
    const float* __restrict__ entity_table,
    const float* __restrict__ relation_table,
    const int*   __restrict__ users,
    float* __restrict__ ws,
    float* __restrict__ out_user)
{
    const int tid = threadIdx.x;
    const int gl  = tid & 15;
    const int t   = blockIdx.x * 16 + (tid >> 4);

    if (t < T_ENT) {
        float4 v = *reinterpret_cast<const float4*>(&entity_table[(size_t)t * DD + gl * 4]);
        float ss = red16(dot4(v, v));
        float sc = fminf(1.0f, __builtin_amdgcn_rsqf(ss));
        if (gl == 0) ws[t] = sc;
    } else if (t < T_USER) {
        int u = t - T_ENT;
        int uid = users[u];
        float4 v = *reinterpret_cast<const float4*>(&user_table[(size_t)uid * DD + gl * 4]);
        float ss = red16(dot4(v, v));
        float sc = fminf(1.0f, __builtin_amdgcn_rsqf(ss));
        v.x *= sc; v.y *= sc; v.z *= sc; v.w *= sc;
        *reinterpret_cast<float4*>(&out_user[(size_t)u * DD + gl * 4]) = v;
    } else if (t < T_ALL) {
        int r = t - T_USER;
        float4 v = *reinterpret_cast<const float4*>(&relation_table[r * DD + gl * 4]);
        float ss = red16(dot4(v, v));
        float sc = fminf(1.0f, __builtin_amdgcn_rsqf(ss));
        v.x *= sc; v.y *= sc; v.z *= sc; v.w *= sc;
        // store swizzled: (r,j) -> r*64 + (j ^ ((r&15)<<2))
        *reinterpret_cast<float4*>(&ws[N_ENT + r * 64 + ((gl * 4) ^ ((r & 15) << 2))]) = v;
    }
}

__global__ __launch_bounds__(512, 8) void kgcn_main(
    const float* __restrict__ entity_table,
    const float* __restrict__ ws,           // [0,N_ENT) scales, then rel (swizzled, renormed)
    const float* __restrict__ W,
    const float* __restrict__ bias,
    const int*   __restrict__ items,
    const int*   __restrict__ adj_entity,
    const int*   __restrict__ adj_relation,
    const float* __restrict__ user_out,     // renormed user vectors (from precompute)
    float* __restrict__ out_final)
{
    // W element (d,j) at Wlds[d*64 + (j ^ ((d&15)<<2))]
    __shared__ __align__(16) float Wlds[64 * 64];
    __shared__ __align__(16) float RelLds[N_REL * DD];
    __shared__ __align__(16) float Vec[8][64];

    const int tid  = threadIdx.x;
    const int lane = tid & 63;
    const int wave = tid >> 6;
    const int grp  = lane >> 4;
    const int gl   = lane & 15;
    const int kk   = lane & 31;

    const int b = blockIdx.x * 8 + wave;
    const int iid = __builtin_amdgcn_readfirstlane(items[b]);

    // ---- early independent loads ----
    const int* abase = (lane < 32) ? adj_entity : adj_relation;
    const int adjv = abase[(size_t)iid * KK_N + kk];   // ent ids | rel ids
    const float sg = ws[adjv];                          // ent scale (lanes<32 meaningful)
    const float isc = ws[iid];
    float4 uv = *reinterpret_cast<const float4*>(&user_out[(size_t)b * DD + gl * 4]);
    float4 iv = *reinterpret_cast<const float4*>(&entity_table[(size_t)iid * DD + gl * 4]);
    const float bv = bias[lane];

    int eid[8];
    #pragma unroll
    for (int k0 = 0; k0 < 8; ++k0)
        eid[k0] = __shfl(adjv, k0 * 4 + grp, 64);
    float4 v[8];
    #pragma unroll
    for (int k0 = 0; k0 < 8; ++k0)
        v[k0] = *reinterpret_cast<const float4*>(&entity_table[(size_t)eid[k0] * DD + gl * 4]);

    // ---- stage W (swizzled) ----
    #pragma unroll
    for (int it = 0; it < 2; ++it) {
        int i = tid + it * 512;                       // float4 index, 1024 total
        float4 w4 = reinterpret_cast<const float4*>(W)[i];
        int d = i >> 4;
        int j = (i & 15) * 4;
        *reinterpret_cast<float4*>(&Wlds[d * 64 + (j ^ ((d & 15) << 2))]) = w4;
    }
    // ---- stage rel (already renormed + swizzled in ws): plain copy ----
    reinterpret_cast<float4*>(RelLds)[tid] = reinterpret_cast<const float4*>(ws + N_ENT)[tid];

    __syncthreads();

    // per-wave u vector into LDS (same-wave ordering, no barrier needed)
    if (lane < 16)
        *reinterpret_cast<float4*>(&Vec[wave][gl * 4]) = uv;

    // ---- scores: lane L -> neighbor L&31, halves split the 64 dims ----
    const int rid  = __shfl(adjv, 32 + kk, 64);
    const int srel = (rid & 15) << 2;
    const float* relrow = &RelLds[rid * 64];
    const int dbase = (lane >> 5) * 32;
    float score = 0.0f;
    #pragma unroll
    for (int d0 = 0; d0 < 32; d0 += 4) {
        int d = dbase + d0;
        float4 rv = *reinterpret_cast<const float4*>(&relrow[d ^ srel]);
        float4 tv = *reinterpret_cast<const float4*>(&Vec[wave][d]);
        score += dot4(tv, rv);
    }
    score += __shfl_xor(score, 32, 64);

    // softmax over 32 neighbors
    float mx = score;
    #pragma unroll
    for (int m = 1; m < 32; m <<= 1) mx = fmaxf(mx, __shfl_xor(mx, m, 64));
    float e = __expf(score - mx);
    float sum = e;
    #pragma unroll
    for (int m = 1; m < 32; m <<= 1) sum += __shfl_xor(sum, m, 64);
    const float wk = e * __builtin_amdgcn_rcpf(sum) * sg;  // attn_k * scale_k on lane k (<32)

    // ---- weighted aggregation of pre-gathered rows ----
    float4 acc = make_float4(0.f, 0.f, 0.f, 0.f);
    #pragma unroll
    for (int k0 = 0; k0 < 8; ++k0) {
        float ck = __shfl(wk, k0 * 4 + grp, 64);
        acc.x = fmaf(ck, v[k0].x, acc.x);
        acc.y = fmaf(ck, v[k0].y, acc.y);
        acc.z = fmaf(ck, v[k0].z, acc.z);
        acc.w = fmaf(ck, v[k0].w, acc.w);
    }
    #pragma unroll
    for (int m = 16; m < 64; m <<= 1) {
        acc.x += __shfl_xor(acc.x, m, 64);
        acc.y += __shfl_xor(acc.y, m, 64);
        acc.z += __shfl_xor(acc.z, m, 64);
        acc.w += __shfl_xor(acc.w, m, 64);
    }

    // ---- item + aggregate -> Vec ----
    float4 tmp;
    tmp.x = fmaf(isc, iv.x, acc.x);
    tmp.y = fmaf(isc, iv.y, acc.y);
    tmp.z = fmaf(isc, iv.z, acc.z);
    tmp.w = fmaf(isc, iv.w, acc.w);
    if (lane < 16)
        *reinterpret_cast<float4*>(&Vec[wave][gl * 4]) = tmp;

    // ---- out = relu(tmp @ W^T + b); lane = output dim ----
    const float* wrow = &Wlds[lane * 64];
    const int twz = (lane & 15) << 2;
    float o = bv;
    #pragma unroll
    for (int j0 = 0; j0 < 64; j0 += 4) {
        float4 wv = *reinterpret_cast<const float4*>(&wrow[j0 ^ twz]);
        float4 tv = *reinterpret_cast<const float4*>(&Vec[wave][j0]);
        o += dot4(tv, wv);
    }
    out_final[(size_t)b * DD + lane] = fmaxf(o, 0.0f);
}

extern "C" void kernel_launch(void* const* d_in, const int* in_sizes, int n_in,
                              void* d_out, int out_size, void* d_ws, size_t ws_size,
                              hipStream_t stream)
{
    const float* user_table     = (const float*)d_in[0];
    const float* entity_table   = (const float*)d_in[1];
    const float* relation_table = (const float*)d_in[2];
    const float* W              = (const float*)d_in[3];
    const float* bias           = (const float*)d_in[4];
    const int*   users          = (const int*)d_in[5];
    const int*   items          = (const int*)d_in[6];
    const int*   adj_entity     = (const int*)d_in[7];
    const int*   adj_relation   = (const int*)d_in[8];

    float* ws        = (float*)d_ws;
    float* out_user  = (float*)d_out;
    float* out_final = (float*)d_out + (size_t)BB * DD;

    precompute<<<(T_ALL + 15) / 16, 256, 0, stream>>>(user_table, entity_table, relation_table,
                                                      users, ws, out_user);
    kgcn_main<<<BB / 8, 512, 0, stream>>>(entity_table, ws, W, bias,
                                          items, adj_entity, adj_relation,
                                          out_user, out_final);
}

// Round 5
// 51.695 us; speedup vs baseline: 1.0921x; 1.0921x over previous
//
#include <hip/hip_runtime.h>
#include <math.h>

#define BB 16384
#define KK_N 32
#define DD 64
#define N_ENT 100000
#define N_REL 32

#define NB_EW ((N_ENT + 63) / 64)   // 1563 blocks: EW = renorm(ent) @ W^T
#define NB_U  (BB / 16)             // 1024 blocks: user renorm -> out_user
#define NB_R  2                     //    2 blocks: rel renorm -> ws (swizzled)
#define GRID_PRE (NB_EW + NB_U + NB_R)

// ws floats: [0, N_ENT*DD) EW ; [N_ENT*DD, +N_REL*DD) rel renormed+swizzled
#define WS_REL_OFF ((size_t)N_ENT * DD)
#define WS_NEED_BYTES ((WS_REL_OFF + (size_t)N_REL * DD) * 4)

__device__ __forceinline__ float dot4(float4 a, float4 b) {
    return a.x * b.x + a.y * b.y + a.z * b.z + a.w * b.w;
}

__device__ __forceinline__ float red16(float ss) {
    ss += __shfl_xor(ss, 1, 64);
    ss += __shfl_xor(ss, 2, 64);
    ss += __shfl_xor(ss, 4, 64);
    ss += __shfl_xor(ss, 8, 64);
    return ss;
}

// ============================ precompute ============================
__global__ __launch_bounds__(256) void precompute(
    const float* __restrict__ user_table,
    const float* __restrict__ entity_table,
    const float* __restrict__ relation_table,
    const float* __restrict__ W,
    const int*   __restrict__ users,
    float* __restrict__ ws,
    float* __restrict__ out_user)
{
    const int tid = threadIdx.x;
    const int blk = blockIdx.x;

    if (blk < NB_EW) {
        // EW[row] = min(1, 1/||ent_row||) * (ent_row @ W^T)
        // lane = row within 64-row tile; wave owns 16 output dims.
        const int lane = tid & 63;
        const int row  = blk * 64 + lane;
        const int d0   = __builtin_amdgcn_readfirstlane(tid >> 6) * 16;
        const int r    = (row < N_ENT) ? row : 0;
        const float* arow = entity_table + (size_t)r * DD;

        float acc[16];
        #pragma unroll
        for (int i = 0; i < 16; ++i) acc[i] = 0.0f;
        float ss = 0.0f;

        #pragma unroll 1
        for (int j0 = 0; j0 < DD; j0 += 4) {
            float4 a = *reinterpret_cast<const float4*>(&arow[j0]);
            ss += dot4(a, a);
            #pragma unroll
            for (int dd = 0; dd < 16; ++dd) {
                float4 w = *reinterpret_cast<const float4*>(&W[(d0 + dd) * DD + j0]);
                acc[dd] = fmaf(a.x, w.x, fmaf(a.y, w.y, fmaf(a.z, w.z, fmaf(a.w, w.w, acc[dd]))));
            }
        }
        float sc = fminf(1.0f, __builtin_amdgcn_rsqf(ss));
        if (row < N_ENT) {
            #pragma unroll
            for (int q = 0; q < 4; ++q) {
                float4 o = make_float4(acc[q*4+0]*sc, acc[q*4+1]*sc, acc[q*4+2]*sc, acc[q*4+3]*sc);
                *reinterpret_cast<float4*>(&ws[(size_t)row * DD + d0 + q * 4]) = o;
            }
        }
    } else if (blk < NB_EW + NB_U) {
        // renormed user vectors -> out_user
        const int gl = tid & 15;
        const int u  = (blk - NB_EW) * 16 + (tid >> 4);
        const int uid = users[u];
        float4 v = *reinterpret_cast<const float4*>(&user_table[(size_t)uid * DD + gl * 4]);
        float ss = red16(dot4(v, v));
        float sc = fminf(1.0f, __builtin_amdgcn_rsqf(ss));
        v.x *= sc; v.y *= sc; v.z *= sc; v.w *= sc;
        *reinterpret_cast<float4*>(&out_user[(size_t)u * DD + gl * 4]) = v;
    } else {
        // renormed relation table -> ws (swizzled: (r,j) -> r*64 + (j ^ ((r&15)<<2)))
        const int gl = tid & 15;
        const int rr = (blk - NB_EW - NB_U) * 16 + (tid >> 4);
        float4 v = *reinterpret_cast<const float4*>(&relation_table[rr * DD + gl * 4]);
        float ss = red16(dot4(v, v));
        float sc = fminf(1.0f, __builtin_amdgcn_rsqf(ss));
        v.x *= sc; v.y *= sc; v.z *= sc; v.w *= sc;
        *reinterpret_cast<float4*>(&ws[WS_REL_OFF + rr * DD + ((gl * 4) ^ ((rr & 15) << 2))]) = v;
    }
}

// ============================ main ============================
__global__ __launch_bounds__(256) void kgcn_main(
    const float* __restrict__ ew,        // ws: renorm(ent) @ W^T
    const float* __restrict__ rel_ws,    // ws + WS_REL_OFF (renormed, swizzled)
    const float* __restrict__ bias,
    const int*   __restrict__ items,
    const int*   __restrict__ adj_entity,
    const int*   __restrict__ adj_relation,
    const float* __restrict__ user_out,  // renormed user vectors
    float* __restrict__ out_final)
{
    __shared__ __align__(16) float RelLds[N_REL * DD];
    __shared__ __align__(16) float Vec[4][64];

    const int tid  = threadIdx.x;
    const int lane = tid & 63;
    const int wave = tid >> 6;
    const int grp  = lane >> 4;
    const int gl   = lane & 15;
    const int kk   = lane & 31;

    const int b = blockIdx.x * 4 + wave;
    const int iid = __builtin_amdgcn_readfirstlane(items[b]);

    // ---- early independent loads ----
    const int* abase = (lane < 32) ? adj_entity : adj_relation;
    const int adjv = abase[(size_t)iid * KK_N + kk];              // ent ids | rel ids
    float4 uv    = *reinterpret_cast<const float4*>(&user_out[(size_t)b * DD + gl * 4]);
    float4 ewi   = *reinterpret_cast<const float4*>(&ew[(size_t)iid * DD + gl * 4]);
    float4 bias4 = *reinterpret_cast<const float4*>(&bias[gl * 4]);

    // gather ids straight from adjacency (L1-hot row; VMEM pipe, not DS)
    int eid[8];
    #pragma unroll
    for (int k0 = 0; k0 < 8; ++k0)
        eid[k0] = adj_entity[(size_t)iid * KK_N + k0 * 4 + grp];
    float4 v[8];
    #pragma unroll
    for (int k0 = 0; k0 < 8; ++k0)
        v[k0] = *reinterpret_cast<const float4*>(&ew[(size_t)eid[k0] * DD + gl * 4]);

    // ---- stage rel table (already renormed + swizzled) ----
    #pragma unroll
    for (int it = 0; it < 2; ++it)
        reinterpret_cast<float4*>(RelLds)[tid + it * 256] =
            reinterpret_cast<const float4*>(rel_ws)[tid + it * 256];
    __syncthreads();

    if (lane < 16)
        *reinterpret_cast<float4*>(&Vec[wave][gl * 4]) = uv;

    // ---- scores: lane L -> neighbor L&31, halves split the 64 dims ----
    const int rid  = __shfl(adjv, 32 + kk, 64);
    const int srel = (rid & 15) << 2;
    const float* relrow = &RelLds[rid * DD];
    const int dbase = (lane >> 5) * 32;
    float score = 0.0f;
    #pragma unroll
    for (int d0 = 0; d0 < 32; d0 += 4) {
        int d = dbase + d0;
        float4 rv = *reinterpret_cast<const float4*>(&relrow[d ^ srel]);
        float4 tv = *reinterpret_cast<const float4*>(&Vec[wave][d]);
        score += dot4(tv, rv);
    }
    score += __shfl_xor(score, 32, 64);

    // ---- softmax over 32 neighbors; |score| <= 1 so no max-subtraction needed ----
    float e = __expf(score);
    float sum = e;
    #pragma unroll
    for (int m = 1; m < 32; m <<= 1) sum += __shfl_xor(sum, m, 64);
    const float wk = e * __builtin_amdgcn_rcpf(sum);

    // ---- weighted aggregation of pre-gathered EW rows ----
    float4 acc = make_float4(0.f, 0.f, 0.f, 0.f);
    #pragma unroll
    for (int k0 = 0; k0 < 8; ++k0) {
        float ck = __shfl(wk, k0 * 4 + grp, 64);
        acc.x = fmaf(ck, v[k0].x, acc.x);
        acc.y = fmaf(ck, v[k0].y, acc.y);
        acc.z = fmaf(ck, v[k0].z, acc.z);
        acc.w = fmaf(ck, v[k0].w, acc.w);
    }
    #pragma unroll
    for (int m = 16; m < 64; m <<= 1) {
        acc.x += __shfl_xor(acc.x, m, 64);
        acc.y += __shfl_xor(acc.y, m, 64);
        acc.z += __shfl_xor(acc.z, m, 64);
        acc.w += __shfl_xor(acc.w, m, 64);
    }

    // ---- out = relu(EW[iid] + sum + b) ----
    if (lane < 16) {
        float4 o;
        o.x = fmaxf(ewi.x + acc.x + bias4.x, 0.0f);
        o.y = fmaxf(ewi.y + acc.y + bias4.y, 0.0f);
        o.z = fmaxf(ewi.z + acc.z + bias4.z, 0.0f);
        o.w = fmaxf(ewi.w + acc.w + bias4.w, 0.0f);
        *reinterpret_cast<float4*>(&out_final[(size_t)b * DD + gl * 4]) = o;
    }
}

// ============================ fallback (round-3, known-good) ============================
__global__ __launch_bounds__(256) void kgcn_fused(
    const float* __restrict__ user_table,
    const float* __restrict__ entity_table,
    const float* __restrict__ relation_table,
    const float* __restrict__ W,
    const float* __restrict__ bias,
    const int*   __restrict__ users,
    const int*   __restrict__ items,
    const int*   __restrict__ adj_entity,
    const int*   __restrict__ adj_relation,
    float* __restrict__ out_user,
    float* __restrict__ out_final)
{
    __shared__ __align__(16) float Wlds[64 * 64];
    __shared__ __align__(16) float RelLds[N_REL * DD];
    __shared__ __align__(16) float Vec[4][64];

    const int tid  = threadIdx.x;
    const int lane = tid & 63;
    const int wave = tid >> 6;
    const int grp  = lane >> 4;
    const int gl   = lane & 15;

    const int b = blockIdx.x * 4 + wave;
    const int uid = __builtin_amdgcn_readfirstlane(users[b]);
    const int iid = __builtin_amdgcn_readfirstlane(items[b]);

    const int kk = lane & 31;
    const int* abase = (lane < 32) ? adj_entity : adj_relation;
    const int adjv = abase[(size_t)iid * KK_N + kk];
    float4 uv = *reinterpret_cast<const float4*>(&user_table[(size_t)uid * DD + gl * 4]);
    float4 iv = *reinterpret_cast<const float4*>(&entity_table[(size_t)iid * DD + gl * 4]);

    #pragma unroll
    for (int it = 0; it < 4; ++it) {
        int i = tid + it * 256;
        float4 w4 = reinterpret_cast<const float4*>(W)[i];
        int d = i >> 4;
        int j = (i & 15) * 4;
        *reinterpret_cast<float4*>(&Wlds[d * 64 + (j ^ ((d & 15) << 2))]) = w4;
    }
    #pragma unroll
    for (int it = 0; it < 2; ++it) {
        int r = wave * 8 + it * 4 + grp;
        float4 vv = reinterpret_cast<const float4*>(relation_table)[r * 16 + gl];
        float ss = dot4(vv, vv);
        #pragma unroll
        for (int m = 1; m < 16; m <<= 1) ss += __shfl_xor(ss, m, 64);
        float sc = fminf(1.0f, __builtin_amdgcn_rsqf(ss));
        vv.x *= sc; vv.y *= sc; vv.z *= sc; vv.w *= sc;
        *reinterpret_cast<float4*>(&RelLds[r * 64 + ((gl * 4) ^ ((r & 15) << 2))]) = vv;
    }

    float ssu = dot4(uv, uv);
    #pragma unroll
    for (int m = 1; m < 16; m <<= 1) ssu += __shfl_xor(ssu, m, 64);
    float usc = fminf(1.0f, __builtin_amdgcn_rsqf(ssu));
    uv.x *= usc; uv.y *= usc; uv.z *= usc; uv.w *= usc;
    if (lane < 16)
        *reinterpret_cast<float4*>(&out_user[(size_t)b * DD + gl * 4]) = uv;

    int eid[8];
    #pragma unroll
    for (int k0 = 0; k0 < 8; ++k0)
        eid[k0] = __shfl(adjv, k0 * 4 + grp, 64);
    float4 v[8];
    #pragma unroll
    for (int k0 = 0; k0 < 8; ++k0)
        v[k0] = *reinterpret_cast<const float4*>(&entity_table[(size_t)eid[k0] * DD + gl * 4]);

    __syncthreads();
    if (lane < 16)
        *reinterpret_cast<float4*>(&Vec[wave][gl * 4]) = uv;

    const int rid = __shfl(adjv, 32 + kk, 64);
    const int srel = (rid & 15) << 2;
    const float* relrow = &RelLds[rid * 64];
    const int dbase = (lane >> 5) * 32;
    float score = 0.0f;
    #pragma unroll
    for (int d0 = 0; d0 < 32; d0 += 4) {
        int d = dbase + d0;
        float4 rv = *reinterpret_cast<const float4*>(&relrow[d ^ srel]);
        float4 tv = *reinterpret_cast<const float4*>(&Vec[wave][d]);
        score += dot4(tv, rv);
    }
    score += __shfl_xor(score, 32, 64);

    float mx = score;
    #pragma unroll
    for (int m = 1; m < 32; m <<= 1) mx = fmaxf(mx, __shfl_xor(mx, m, 64));
    float e = __expf(score - mx);
    float sum = e;
    #pragma unroll
    for (int m = 1; m < 32; m <<= 1) sum += __shfl_xor(sum, m, 64);
    const float attn = e * __builtin_amdgcn_rcpf(sum);

    float cc[8];
    #pragma unroll
    for (int k0 = 0; k0 < 8; ++k0)
        cc[k0] = __shfl(attn, k0 * 4 + grp, 64);

    float4 acc = make_float4(0.f, 0.f, 0.f, 0.f);
    #pragma unroll
    for (int k0 = 0; k0 < 8; ++k0) {
        float ss = dot4(v[k0], v[k0]);
        #pragma unroll
        for (int m = 1; m < 16; m <<= 1) ss += __shfl_xor(ss, m, 64);
        float sc = fminf(1.0f, __builtin_amdgcn_rsqf(ss));
        float ck = cc[k0] * sc;
        acc.x = fmaf(ck, v[k0].x, acc.x);
        acc.y = fmaf(ck, v[k0].y, acc.y);
        acc.z = fmaf(ck, v[k0].z, acc.z);
        acc.w = fmaf(ck, v[k0].w, acc.w);
    }
    #pragma unroll
    for (int m = 16; m < 64; m <<= 1) {
        acc.x += __shfl_xor(acc.x, m, 64);
        acc.y += __shfl_xor(acc.y, m, 64);
        acc.z += __shfl_xor(acc.z, m, 64);
        acc.w += __shfl_xor(acc.w, m, 64);
    }

    float ssi = dot4(iv, iv);
    #pragma unroll
    for (int m = 1; m < 16; m <<= 1) ssi += __shfl_xor(ssi, m, 64);
    float isc = fminf(1.0f, __builtin_amdgcn_rsqf(ssi));
    float4 tmp;
    tmp.x = fmaf(isc, iv.x, acc.x);
    tmp.y = fmaf(isc, iv.y, acc.y);
    tmp.z = fmaf(isc, iv.z, acc.z);
    tmp.w = fmaf(isc, iv.w, acc.w);
    if (lane < 16)
        *reinterpret_cast<float4*>(&Vec[wave][gl * 4]) = tmp;

    const float bv = bias[lane];
    const float* wrow = &Wlds[lane * 64];
    const int twz = (lane & 15) << 2;
    float o = bv;
    #pragma unroll
    for (int j0 = 0; j0 < 64; j0 += 4) {
        float4 wv = *reinterpret_cast<const float4*>(&wrow[j0 ^ twz]);
        float4 tv = *reinterpret_cast<const float4*>(&Vec[wave][j0]);
        o += dot4(tv, wv);
    }
    out_final[(size_t)b * DD + lane] = fmaxf(o, 0.0f);
}

extern "C" void kernel_launch(void* const* d_in, const int* in_sizes, int n_in,
                              void* d_out, int out_size, void* d_ws, size_t ws_size,
                              hipStream_t stream)
{
    const float* user_table     = (const float*)d_in[0];
    const float* entity_table   = (const float*)d_in[1];
    const float* relation_table = (const float*)d_in[2];
    const float* W              = (const float*)d_in[3];
    const float* bias           = (const float*)d_in[4];
    const int*   users          = (const int*)d_in[5];
    const int*   items          = (const int*)d_in[6];
    const int*   adj_entity     = (const int*)d_in[7];
    const int*   adj_relation   = (const int*)d_in[8];

    float* ws        = (float*)d_ws;
    float* out_user  = (float*)d_out;
    float* out_final = (float*)d_out + (size_t)BB * DD;

    if (ws_size >= WS_NEED_BYTES) {
        precompute<<<GRID_PRE, 256, 0, stream>>>(user_table, entity_table, relation_table,
                                                 W, users, ws, out_user);
        kgcn_main<<<BB / 4, 256, 0, stream>>>(ws, ws + WS_REL_OFF, bias,
                                              items, adj_entity, adj_relation,
                                              out_user, out_final);
    } else {
        kgcn_fused<<<BB / 4, 256, 0, stream>>>(user_table, entity_table, relation_table,
                                               W, bias, users, items, adj_entity, adj_relation,
                                               out_user, out_final);
    }
}

// Round 6
// 30.252 us; speedup vs baseline: 1.8662x; 1.7088x over previous
//
#include <hip/hip_runtime.h>
#include <math.h>

#define BB 16384
#define KK_N 32
#define DD 64
#define N_ENT 100000
#define N_REL 32

// ws bytes: [0, N_ENT*128) bf16 renormed entity rows (128 B/row)
//           then N_REL*DD floats: renormed + swizzled relation table
#define WS_REL_OFF_BYTES ((size_t)N_ENT * DD * 2)
#define WS_NEED_BYTES (WS_REL_OFF_BYTES + (size_t)N_REL * DD * 4)

#define PT_ENT  N_ENT
#define PT_USER (N_ENT + BB)
#define PT_ALL  (N_ENT + BB + N_REL)

__device__ __forceinline__ float dot4(float4 a, float4 b) {
    return a.x * b.x + a.y * b.y + a.z * b.z + a.w * b.w;
}

__device__ __forceinline__ float red16(float ss) {
    ss += __shfl_xor(ss, 1, 64);
    ss += __shfl_xor(ss, 2, 64);
    ss += __shfl_xor(ss, 4, 64);
    ss += __shfl_xor(ss, 8, 64);
    return ss;
}

__device__ __forceinline__ unsigned short f2bf(float x) {
    unsigned int u = __float_as_uint(x);
    u += 0x7fffu + ((u >> 16) & 1u);   // round-to-nearest-even
    return (unsigned short)(u >> 16);
}

__device__ __forceinline__ float bf2f(unsigned short h) {
    return __uint_as_float(((unsigned int)h) << 16);
}

__device__ __forceinline__ float4 bf4(ushort4 h) {
    return make_float4(bf2f(h.x), bf2f(h.y), bf2f(h.z), bf2f(h.w));
}

// ============================ precompute (all coalesced) ============================
__global__ __launch_bounds__(256) void precompute(
    const float* __restrict__ user_table,
    const float* __restrict__ entity_table,
    const float* __restrict__ relation_table,
    const int*   __restrict__ users,
    unsigned short* __restrict__ ent_bf,
    float* __restrict__ rel_ws,
    float* __restrict__ out_user)
{
    const int tid = threadIdx.x;
    const int gl  = tid & 15;
    const int t   = blockIdx.x * 16 + (tid >> 4);
    if (t >= PT_ALL) return;

    if (t < PT_ENT) {
        float4 v = *reinterpret_cast<const float4*>(&entity_table[(size_t)t * DD + gl * 4]);
        float ss = red16(dot4(v, v));
        float sc = fminf(1.0f, __builtin_amdgcn_rsqf(ss));
        ushort4 h;
        h.x = f2bf(v.x * sc); h.y = f2bf(v.y * sc);
        h.z = f2bf(v.z * sc); h.w = f2bf(v.w * sc);
        *reinterpret_cast<ushort4*>(&ent_bf[(size_t)t * DD + gl * 4]) = h;
    } else if (t < PT_USER) {
        int u = t - PT_ENT;
        int uid = users[u];
        float4 v = *reinterpret_cast<const float4*>(&user_table[(size_t)uid * DD + gl * 4]);
        float ss = red16(dot4(v, v));
        float sc = fminf(1.0f, __builtin_amdgcn_rsqf(ss));
        v.x *= sc; v.y *= sc; v.z *= sc; v.w *= sc;
        *reinterpret_cast<float4*>(&out_user[(size_t)u * DD + gl * 4]) = v;
    } else {
        int rr = t - PT_USER;
        float4 v = *reinterpret_cast<const float4*>(&relation_table[rr * DD + gl * 4]);
        float ss = red16(dot4(v, v));
        float sc = fminf(1.0f, __builtin_amdgcn_rsqf(ss));
        v.x *= sc; v.y *= sc; v.z *= sc; v.w *= sc;
        *reinterpret_cast<float4*>(&rel_ws[rr * DD + ((gl * 4) ^ ((rr & 15) << 2))]) = v;
    }
}

// ============================ main: 4 waves/block, 2 batch elems per wave ============================
__global__ __launch_bounds__(256, 4) void kgcn_main(
    const unsigned short* __restrict__ ent_bf,
    const float* __restrict__ rel_ws,
    const float* __restrict__ W,
    const float* __restrict__ bias,
    const int*   __restrict__ items,
    const int*   __restrict__ adj_entity,
    const int*   __restrict__ adj_relation,
    const float* __restrict__ user_out,
    float* __restrict__ out_final)
{
    __shared__ __align__(16) float Wlds[64 * 64];
    __shared__ __align__(16) float RelLds[N_REL * DD];
    __shared__ __align__(16) float Vec[4][2][64];

    const int tid  = threadIdx.x;
    const int lane = tid & 63;
    const int wave = tid >> 6;
    const int grp  = lane >> 4;
    const int gl   = lane & 15;
    const int kk   = lane & 31;

    const int b0 = (blockIdx.x * 4 + wave) * 2;
    const int iid0 = __builtin_amdgcn_readfirstlane(items[b0]);
    const int iid1 = __builtin_amdgcn_readfirstlane(items[b0 + 1]);

    // ---- early independent loads (VMEM pipe) ----
    const int* abase = (lane < 32) ? adj_entity : adj_relation;
    const int adjv0 = abase[(size_t)iid0 * KK_N + kk];
    const int adjv1 = abase[(size_t)iid1 * KK_N + kk];

    int eid0[8], eid1[8];
    #pragma unroll
    for (int k0 = 0; k0 < 8; ++k0) {
        eid0[k0] = adj_entity[(size_t)iid0 * KK_N + k0 * 4 + grp];   // L1-hot row
        eid1[k0] = adj_entity[(size_t)iid1 * KK_N + k0 * 4 + grp];
    }
    ushort4 v0[8], v1[8];
    #pragma unroll
    for (int k0 = 0; k0 < 8; ++k0) {
        v0[k0] = *reinterpret_cast<const ushort4*>(&ent_bf[(size_t)eid0[k0] * DD + gl * 4]);
        v1[k0] = *reinterpret_cast<const ushort4*>(&ent_bf[(size_t)eid1[k0] * DD + gl * 4]);
    }
    float4 uv0 = *reinterpret_cast<const float4*>(&user_out[(size_t)b0 * DD + gl * 4]);
    float4 uv1 = *reinterpret_cast<const float4*>(&user_out[(size_t)(b0 + 1) * DD + gl * 4]);
    ushort4 it0 = *reinterpret_cast<const ushort4*>(&ent_bf[(size_t)iid0 * DD + gl * 4]);
    ushort4 it1 = *reinterpret_cast<const ushort4*>(&ent_bf[(size_t)iid1 * DD + gl * 4]);

    // ---- stage W (swizzled): (d,j) -> d*64 + (j ^ ((d&15)<<2)) ----
    #pragma unroll
    for (int it = 0; it < 4; ++it) {
        int i = tid + it * 256;
        float4 w4 = reinterpret_cast<const float4*>(W)[i];
        int d = i >> 4;
        int j = (i & 15) * 4;
        *reinterpret_cast<float4*>(&Wlds[d * 64 + (j ^ ((d & 15) << 2))]) = w4;
    }
    // ---- stage rel table (already renormed + swizzled) ----
    #pragma unroll
    for (int it = 0; it < 2; ++it)
        reinterpret_cast<float4*>(RelLds)[tid + it * 256] =
            reinterpret_cast<const float4*>(rel_ws)[tid + it * 256];
    __syncthreads();

    if (lane < 16) {
        *reinterpret_cast<float4*>(&Vec[wave][0][gl * 4]) = uv0;
        *reinterpret_cast<float4*>(&Vec[wave][1][gl * 4]) = uv1;
    }

    // ---- scores: lane L -> neighbor L&31; halves split the 64 dims ----
    const int rid0 = __shfl(adjv0, 32 + kk, 64);
    const int rid1 = __shfl(adjv1, 32 + kk, 64);
    const int sz0 = (rid0 & 15) << 2;
    const int sz1 = (rid1 & 15) << 2;
    const int dbase = (lane >> 5) * 32;
    float s0 = 0.0f, s1 = 0.0f;
    #pragma unroll
    for (int d0 = 0; d0 < 32; d0 += 4) {
        int d = dbase + d0;
        float4 q0 = *reinterpret_cast<const float4*>(&Vec[wave][0][d]);
        float4 r0 = *reinterpret_cast<const float4*>(&RelLds[rid0 * DD + (d ^ sz0)]);
        s0 += dot4(q0, r0);
        float4 q1 = *reinterpret_cast<const float4*>(&Vec[wave][1][d]);
        float4 r1 = *reinterpret_cast<const float4*>(&RelLds[rid1 * DD + (d ^ sz1)]);
        s1 += dot4(q1, r1);
    }
    s0 += __shfl_xor(s0, 32, 64);
    s1 += __shfl_xor(s1, 32, 64);

    // ---- softmax over 32 neighbors; |score| <= 1 so exp is safe without max-pass ----
    float e0 = __expf(s0), e1 = __expf(s1);
    float sum0 = e0, sum1 = e1;
    #pragma unroll
    for (int m = 1; m < 32; m <<= 1) {
        sum0 += __shfl_xor(sum0, m, 64);
        sum1 += __shfl_xor(sum1, m, 64);
    }
    const float wk0 = e0 * __builtin_amdgcn_rcpf(sum0);
    const float wk1 = e1 * __builtin_amdgcn_rcpf(sum1);

    // ---- weighted aggregation of pre-gathered (pre-renormed) bf16 rows ----
    float4 acc0 = make_float4(0.f, 0.f, 0.f, 0.f);
    float4 acc1 = make_float4(0.f, 0.f, 0.f, 0.f);
    #pragma unroll
    for (int k0 = 0; k0 < 8; ++k0) {
        float c0 = __shfl(wk0, k0 * 4 + grp, 64);
        float4 f0 = bf4(v0[k0]);
        acc0.x = fmaf(c0, f0.x, acc0.x);
        acc0.y = fmaf(c0, f0.y, acc0.y);
        acc0.z = fmaf(c0, f0.z, acc0.z);
        acc0.w = fmaf(c0, f0.w, acc0.w);
        float c1 = __shfl(wk1, k0 * 4 + grp, 64);
        float4 f1 = bf4(v1[k0]);
        acc1.x = fmaf(c1, f1.x, acc1.x);
        acc1.y = fmaf(c1, f1.y, acc1.y);
        acc1.z = fmaf(c1, f1.z, acc1.z);
        acc1.w = fmaf(c1, f1.w, acc1.w);
    }
    #pragma unroll
    for (int m = 16; m < 64; m <<= 1) {
        acc0.x += __shfl_xor(acc0.x, m, 64);
        acc0.y += __shfl_xor(acc0.y, m, 64);
        acc0.z += __shfl_xor(acc0.z, m, 64);
        acc0.w += __shfl_xor(acc0.w, m, 64);
        acc1.x += __shfl_xor(acc1.x, m, 64);
        acc1.y += __shfl_xor(acc1.y, m, 64);
        acc1.z += __shfl_xor(acc1.z, m, 64);
        acc1.w += __shfl_xor(acc1.w, m, 64);
    }

    // ---- item + aggregate -> Vec (same-wave LDS ordering) ----
    float4 f0 = bf4(it0), f1 = bf4(it1);
    float4 t0 = make_float4(f0.x + acc0.x, f0.y + acc0.y, f0.z + acc0.z, f0.w + acc0.w);
    float4 t1 = make_float4(f1.x + acc1.x, f1.y + acc1.y, f1.z + acc1.z, f1.w + acc1.w);
    if (lane < 16) {
        *reinterpret_cast<float4*>(&Vec[wave][0][gl * 4]) = t0;
        *reinterpret_cast<float4*>(&Vec[wave][1][gl * 4]) = t1;
    }

    // ---- out = relu(tmp @ W^T + b); lane = output dim; W read shared by both elems ----
    const float bv = bias[lane];
    const float* wrow = &Wlds[lane * 64];
    const int twz = (lane & 15) << 2;
    float o0 = bv, o1 = bv;
    #pragma unroll
    for (int j0 = 0; j0 < 64; j0 += 4) {
        float4 wv = *reinterpret_cast<const float4*>(&wrow[j0 ^ twz]);
        float4 q0 = *reinterpret_cast<const float4*>(&Vec[wave][0][j0]);
        float4 q1 = *reinterpret_cast<const float4*>(&Vec[wave][1][j0]);
        o0 += dot4(q0, wv);
        o1 += dot4(q1, wv);
    }
    out_final[(size_t)b0 * DD + lane] = fmaxf(o0, 0.0f);
    out_final[(size_t)(b0 + 1) * DD + lane] = fmaxf(o1, 0.0f);
}

// ============================ fallback (round-3, known-good) ============================
__global__ __launch_bounds__(256) void kgcn_fused(
    const float* __restrict__ user_table,
    const float* __restrict__ entity_table,
    const float* __restrict__ relation_table,
    const float* __restrict__ W,
    const float* __restrict__ bias,
    const int*   __restrict__ users,
    const int*   __restrict__ items,
    const int*   __restrict__ adj_entity,
    const int*   __restrict__ adj_relation,
    float* __restrict__ out_user,
    float* __restrict__ out_final)
{
    __shared__ __align__(16) float Wlds[64 * 64];
    __shared__ __align__(16) float RelLds[N_REL * DD];
    __shared__ __align__(16) float Vec[4][64];

    const int tid  = threadIdx.x;
    const int lane = tid & 63;
    const int wave = tid >> 6;
    const int grp  = lane >> 4;
    const int gl   = lane & 15;

    const int b = blockIdx.x * 4 + wave;
    const int uid = __builtin_amdgcn_readfirstlane(users[b]);
    const int iid = __builtin_amdgcn_readfirstlane(items[b]);

    const int kk = lane & 31;
    const int* abase = (lane < 32) ? adj_entity : adj_relation;
    const int adjv = abase[(size_t)iid * KK_N + kk];
    float4 uv = *reinterpret_cast<const float4*>(&user_table[(size_t)uid * DD + gl * 4]);
    float4 iv = *reinterpret_cast<const float4*>(&entity_table[(size_t)iid * DD + gl * 4]);

    #pragma unroll
    for (int it = 0; it < 4; ++it) {
        int i = tid + it * 256;
        float4 w4 = reinterpret_cast<const float4*>(W)[i];
        int d = i >> 4;
        int j = (i & 15) * 4;
        *reinterpret_cast<float4*>(&Wlds[d * 64 + (j ^ ((d & 15) << 2))]) = w4;
    }
    #pragma unroll
    for (int it = 0; it < 2; ++it) {
        int r = wave * 8 + it * 4 + grp;
        float4 vv = reinterpret_cast<const float4*>(relation_table)[r * 16 + gl];
        float ss = red16(dot4(vv, vv));
        float sc = fminf(1.0f, __builtin_amdgcn_rsqf(ss));
        vv.x *= sc; vv.y *= sc; vv.z *= sc; vv.w *= sc;
        *reinterpret_cast<float4*>(&RelLds[r * 64 + ((gl * 4) ^ ((r & 15) << 2))]) = vv;
    }

    float ssu = red16(dot4(uv, uv));
    float usc = fminf(1.0f, __builtin_amdgcn_rsqf(ssu));
    uv.x *= usc; uv.y *= usc; uv.z *= usc; uv.w *= usc;
    if (lane < 16)
        *reinterpret_cast<float4*>(&out_user[(size_t)b * DD + gl * 4]) = uv;

    int eid[8];
    #pragma unroll
    for (int k0 = 0; k0 < 8; ++k0)
        eid[k0] = __shfl(adjv, k0 * 4 + grp, 64);
    float4 v[8];
    #pragma unroll
    for (int k0 = 0; k0 < 8; ++k0)
        v[k0] = *reinterpret_cast<const float4*>(&entity_table[(size_t)eid[k0] * DD + gl * 4]);

    __syncthreads();
    if (lane < 16)
        *reinterpret_cast<float4*>(&Vec[wave][gl * 4]) = uv;

    const int rid = __shfl(adjv, 32 + kk, 64);
    const int srel = (rid & 15) << 2;
    const float* relrow = &RelLds[rid * 64];
    const int dbase = (lane >> 5) * 32;
    float score = 0.0f;
    #pragma unroll
    for (int d0 = 0; d0 < 32; d0 += 4) {
        int d = dbase + d0;
        float4 rv = *reinterpret_cast<const float4*>(&relrow[d ^ srel]);
        float4 tv = *reinterpret_cast<const float4*>(&Vec[wave][d]);
        score += dot4(tv, rv);
    }
    score += __shfl_xor(score, 32, 64);

    float mx = score;
    #pragma unroll
    for (int m = 1; m < 32; m <<= 1) mx = fmaxf(mx, __shfl_xor(mx, m, 64));
    float e = __expf(score - mx);
    float sum = e;
    #pragma unroll
    for (int m = 1; m < 32; m <<= 1) sum += __shfl_xor(sum, m, 64);
    const float attn = e * __builtin_amdgcn_rcpf(sum);

    float cc[8];
    #pragma unroll
    for (int k0 = 0; k0 < 8; ++k0)
        cc[k0] = __shfl(attn, k0 * 4 + grp, 64);

    float4 acc = make_float4(0.f, 0.f, 0.f, 0.f);
    #pragma unroll
    for (int k0 = 0; k0 < 8; ++k0) {
        float ss = red16(dot4(v[k0], v[k0]));
        float sc = fminf(1.0f, __builtin_amdgcn_rsqf(ss));
        float ck = cc[k0] * sc;
        acc.x = fmaf(ck, v[k0].x, acc.x);
        acc.y = fmaf(ck, v[k0].y, acc.y);
        acc.z = fmaf(ck, v[k0].z, acc.z);
        acc.w = fmaf(ck, v[k0].w, acc.w);
    }
    #pragma unroll
    for (int m = 16; m < 64; m <<= 1) {
        acc.x += __shfl_xor(acc.x, m, 64);
        acc.y += __shfl_xor(acc.y, m, 64);
        acc.z += __shfl_xor(acc.z, m, 64);
        acc.w += __shfl_xor(acc.w, m, 64);
    }

    float ssi = red16(dot4(iv, iv));
    float isc = fminf(1.0f, __builtin_amdgcn_rsqf(ssi));
    float4 tmp;
    tmp.x = fmaf(isc, iv.x, acc.x);
    tmp.y = fmaf(isc, iv.y, acc.y);
    tmp.z = fmaf(isc, iv.z, acc.z);
    tmp.w = fmaf(isc, iv.w, acc.w);
    if (lane < 16)
        *reinterpret_cast<float4*>(&Vec[wave][gl * 4]) = tmp;

    const float bv = bias[lane];
    const float* wrow = &Wlds[lane * 64];
    const int twz = (lane & 15) << 2;
    float o = bv;
    #pragma unroll
    for (int j0 = 0; j0 < 64; j0 += 4) {
        float4 wv = *reinterpret_cast<const float4*>(&wrow[j0 ^ twz]);
        float4 tv = *reinterpret_cast<const float4*>(&Vec[wave][j0]);
        o += dot4(tv, wv);
    }
    out_final[(size_t)b * DD + lane] = fmaxf(o, 0.0f);
}

extern "C" void kernel_launch(void* const* d_in, const int* in_sizes, int n_in,
                              void* d_out, int out_size, void* d_ws, size_t ws_size,
                              hipStream_t stream)
{
    const float* user_table     = (const float*)d_in[0];
    const float* entity_table   = (const float*)d_in[1];
    const float* relation_table = (const float*)d_in[2];
    const float* W              = (const float*)d_in[3];
    const float* bias           = (const float*)d_in[4];
    const int*   users          = (const int*)d_in[5];
    const int*   items          = (const int*)d_in[6];
    const int*   adj_entity     = (const int*)d_in[7];
    const int*   adj_relation   = (const int*)d_in[8];

    float* out_user  = (float*)d_out;
    float* out_final = (float*)d_out + (size_t)BB * DD;

    if (ws_size >= WS_NEED_BYTES) {
        unsigned short* ent_bf = (unsigned short*)d_ws;
        float* rel_ws = (float*)((char*)d_ws + WS_REL_OFF_BYTES);
        precompute<<<(PT_ALL + 15) / 16, 256, 0, stream>>>(
            user_table, entity_table, relation_table, users, ent_bf, rel_ws, out_user);
        kgcn_main<<<BB / 8, 256, 0, stream>>>(
            ent_bf, rel_ws, W, bias, items, adj_entity, adj_relation, out_user, out_final);
    } else {
        kgcn_fused<<<BB / 4, 256, 0, stream>>>(user_table, entity_table, relation_table,
                                               W, bias, users, items, adj_entity, adj_relation,
                                               out_user, out_final);
    }
}